// Round 1
// baseline (573.904 us; speedup 1.0000x reference)
//
#include <hip/hip_runtime.h>

#define S_LEN   2048
#define D_MODEL 1024
#define NB      4
#define NH      16
#define DEP     64
#define NHEADS  64      // NH*NB
#define M_ROWS  8192    // NB*S_LEN

typedef __bf16 bf16_t;
typedef bf16_t bf16x8 __attribute__((ext_vector_type(8)));
typedef float  f32x4  __attribute__((ext_vector_type(4)));

#define LOG2E 1.4426950408889634f

#if __has_builtin(__builtin_amdgcn_exp2f)
  #define EXP2(x) __builtin_amdgcn_exp2f(x)
#else
  #define EXP2(x) exp2f(x)
#endif

#define GLOBAL_AS(p) ((const __attribute__((address_space(1))) void*)(p))
#define LDS_AS(p)    ((__attribute__((address_space(3))) void*)(p))

__device__ __forceinline__ unsigned short bf16r(float f) {
  unsigned u = __builtin_bit_cast(unsigned, f);
  u = (u + 0x7FFFu + ((u >> 16) & 1u)) >> 16;
  return (unsigned short)u;
}

// ---------------- fp32 -> bf16 convert (linear) ----------------
__global__ __launch_bounds__(256) void cvt_f32_bf16(
    const float* __restrict__ in, unsigned short* __restrict__ out, int n4) {
  int i = blockIdx.x * 256 + threadIdx.x;
  if (i >= n4) return;
  float4 v = reinterpret_cast<const float4*>(in)[i];
  ushort4 o;
  o.x = bf16r(v.x); o.y = bf16r(v.y); o.z = bf16r(v.z); o.w = bf16r(v.w);
  reinterpret_cast<ushort4*>(out)[i] = o;
}

// ---------------- W (K,N) fp32 -> Wt (N,K) bf16 ----------------
__global__ __launch_bounds__(256) void transpose_cvt_w(
    const float* __restrict__ in, unsigned short* __restrict__ out) {
  __shared__ unsigned short tile[32][33];
  int bx = blockIdx.x * 32;  // n base
  int by = blockIdx.y * 32;  // k base
  int tx = threadIdx.x & 31, ty = threadIdx.x >> 5; // 32x8
  for (int i = ty; i < 32; i += 8)
    tile[i][tx] = bf16r(in[(by + i) * D_MODEL + bx + tx]);
  __syncthreads();
  for (int i = ty; i < 32; i += 8)
    out[(size_t)(bx + i) * D_MODEL + by + tx] = tile[tx][i];
}

// ---------------- bf16 GEMM: (8192,1024) @ W(k,n) -> head-major bf16 ------
// A: (M,1024) bf16 row-major. Bt: (1024,1024) bf16 = W^T (Bt[n][k]).
// out[(h*NB+b)][s][d] bf16, with (acc+bias)*scale.
__global__ __launch_bounds__(256) void gemm_qkv(
    const unsigned short* __restrict__ A,
    const unsigned short* __restrict__ Bt,
    const float* __restrict__ bias,
    unsigned short* __restrict__ out,
    float scale) {
  __shared__ __align__(16) unsigned short Asb[128 * 32];
  __shared__ __align__(16) unsigned short Bsb[128 * 32];
  int tid = threadIdx.x, lane = tid & 63, wid = tid >> 6;
  int lr = lane & 15, lg = lane >> 4;
  int m0 = blockIdx.x * 128, n0 = blockIdx.y * 128;
  int wr = wid >> 1, wc = wid & 1;
  f32x4 acc[4][4] = {};
  for (int kt = 0; kt < D_MODEL / 32; kt++) {
    int k0 = kt * 32;
#pragma unroll
    for (int i = 0; i < 2; i++) {
      int chunk = i * 256 + wid * 64 + lane;      // 512 chunks of 8 elts
      int r = chunk >> 2, c = (chunk & 3) * 8;
      __builtin_amdgcn_global_load_lds(
          GLOBAL_AS(A + (size_t)(m0 + r) * D_MODEL + k0 + c),
          LDS_AS(Asb + (size_t)(i * 256 + wid * 64) * 8), 16, 0, 0);
      __builtin_amdgcn_global_load_lds(
          GLOBAL_AS(Bt + (size_t)(n0 + r) * D_MODEL + k0 + c),
          LDS_AS(Bsb + (size_t)(i * 256 + wid * 64) * 8), 16, 0, 0);
    }
    __syncthreads();
    bf16x8 af[4], bfr[4];
#pragma unroll
    for (int mi = 0; mi < 4; mi++)
      af[mi] = *(const bf16x8*)(Asb + (wr * 64 + mi * 16 + lr) * 32 + lg * 8);
#pragma unroll
    for (int ni = 0; ni < 4; ni++)
      bfr[ni] = *(const bf16x8*)(Bsb + (wc * 64 + ni * 16 + lr) * 32 + lg * 8);
#pragma unroll
    for (int mi = 0; mi < 4; mi++)
#pragma unroll
      for (int ni = 0; ni < 4; ni++)
        acc[mi][ni] = __builtin_amdgcn_mfma_f32_16x16x32_bf16(
            af[mi], bfr[ni], acc[mi][ni], 0, 0, 0);
    __syncthreads();
  }
  // epilogue: head-major bf16 write
#pragma unroll
  for (int mi = 0; mi < 4; mi++) {
#pragma unroll
    for (int ni = 0; ni < 4; ni++) {
      int col = n0 + wc * 64 + ni * 16 + lr;
      float bv = bias[col];
      int h = col >> 6, d = col & 63;
#pragma unroll
      for (int r = 0; r < 4; r++) {
        int row = m0 + wr * 64 + mi * 16 + lg * 4 + r;
        int b = row >> 11, s = row & (S_LEN - 1);
        float v = (acc[mi][ni][r] + bv) * scale;
        out[((size_t)(h * NB + b) * S_LEN + s) * DEP + d] = bf16r(v);
      }
    }
  }
}

// ---------------- V head-major (n,s,d) -> Vt (n,d,s) ----------------
__global__ __launch_bounds__(256) void transpose_v(
    const unsigned short* __restrict__ in, unsigned short* __restrict__ out) {
  __shared__ unsigned short t[64][65];
  int n = blockIdx.y, s0 = blockIdx.x * 64;
  for (int i = 0; i < 16; i++) {
    int idx = i * 256 + threadIdx.x;
    int r = idx >> 6, c = idx & 63;
    t[r][c] = in[((size_t)n * S_LEN + s0 + r) * DEP + c];
  }
  __syncthreads();
  for (int i = 0; i < 16; i++) {
    int idx = i * 256 + threadIdx.x;
    int d = idx >> 6, c = idx & 63;
    out[((size_t)n * DEP + d) * S_LEN + s0 + c] = t[c][d];
  }
}

// ---------------- causal flash attention ----------------
// Q,K head-major (64,2048,64) bf16 (Q pre-scaled by 0.125), Vt (64,64,2048).
// out fp32 (4,2048,1024) merged-head layout.
__global__ __launch_bounds__(256) void attn_fwd(
    const unsigned short* __restrict__ Q,
    const unsigned short* __restrict__ K,
    const unsigned short* __restrict__ Vt,
    float* __restrict__ out) {
  __shared__ __align__(16) unsigned short plds[4][16 * 64];  // 2KB per wave
  int tid = threadIdx.x, lane = tid & 63, wid = tid >> 6;
  int lr = lane & 15, lg = lane >> 4;
  int n = blockIdx.y;
  int q0 = blockIdx.x * 64;
  int qw = q0 + wid * 16;
  const unsigned short* Qh = Q + (size_t)n * S_LEN * DEP;
  const unsigned short* Kh = K + (size_t)n * S_LEN * DEP;
  const unsigned short* Vh = Vt + (size_t)n * DEP * S_LEN;

  bf16x8 aq[2];
  aq[0] = *(const bf16x8*)(Qh + (qw + lr) * DEP + lg * 8);
  aq[1] = *(const bf16x8*)(Qh + (qw + lr) * DEP + 32 + lg * 8);

  f32x4 o[4] = {};
  float mrow[4] = {-__builtin_inff(), -__builtin_inff(),
                   -__builtin_inff(), -__builtin_inff()};
  float lrow[4] = {0.f, 0.f, 0.f, 0.f};

  unsigned short* pw = &plds[wid][0];
  int nt = blockIdx.x + 1;
  for (int t = 0; t < nt; t++) {
    int kv = t * 64;
    f32x4 sacc[4] = {};
#pragma unroll
    for (int ct = 0; ct < 4; ct++) {
      bf16x8 kf0 = *(const bf16x8*)(Kh + (kv + ct * 16 + lr) * DEP + lg * 8);
      bf16x8 kf1 = *(const bf16x8*)(Kh + (kv + ct * 16 + lr) * DEP + 32 + lg * 8);
      sacc[ct] = __builtin_amdgcn_mfma_f32_16x16x32_bf16(aq[0], kf0, sacc[ct], 0, 0, 0);
      sacc[ct] = __builtin_amdgcn_mfma_f32_16x16x32_bf16(aq[1], kf1, sacc[ct], 0, 0, 0);
    }
    if (t == nt - 1) {  // diagonal tile: causal mask
#pragma unroll
      for (int ct = 0; ct < 4; ct++) {
        int col = kv + ct * 16 + lr;
#pragma unroll
        for (int r = 0; r < 4; r++) {
          int row = qw + lg * 4 + r;
          if (col > row) sacc[ct][r] = -3.0e38f;
        }
      }
    }
    // online softmax (per row; rows spread over 4 regs, cols over 16 lanes)
    float alpha[4];
#pragma unroll
    for (int r = 0; r < 4; r++) {
      float mx = fmaxf(fmaxf(sacc[0][r], sacc[1][r]), fmaxf(sacc[2][r], sacc[3][r]));
      mx = fmaxf(mx, __shfl_xor(mx, 1));
      mx = fmaxf(mx, __shfl_xor(mx, 2));
      mx = fmaxf(mx, __shfl_xor(mx, 4));
      mx = fmaxf(mx, __shfl_xor(mx, 8));
      float mn = fmaxf(mrow[r], mx);
      alpha[r] = EXP2((mrow[r] - mn) * LOG2E);
      mrow[r] = mn;
    }
#pragma unroll
    for (int r = 0; r < 4; r++) {
      float s = 0.f;
#pragma unroll
      for (int ct = 0; ct < 4; ct++) {
        float p = EXP2((sacc[ct][r] - mrow[r]) * LOG2E);
        sacc[ct][r] = p;
        s += p;
      }
      s += __shfl_xor(s, 1);
      s += __shfl_xor(s, 2);
      s += __shfl_xor(s, 4);
      s += __shfl_xor(s, 8);
      lrow[r] = lrow[r] * alpha[r] + s;
      o[0][r] *= alpha[r]; o[1][r] *= alpha[r];
      o[2][r] *= alpha[r]; o[3][r] *= alpha[r];
    }
    // P (acc layout) -> LDS (A-frag layout), XOR-swizzled
#pragma unroll
    for (int ct = 0; ct < 4; ct++)
#pragma unroll
      for (int r = 0; r < 4; r++) {
        int row = lg * 4 + r, col = ct * 16 + lr;
        int ba = (row * 128 + col * 2) ^ ((row & 7) << 4);
        *(unsigned short*)((char*)pw + ba) = bf16r(sacc[ct][r]);
      }
    asm volatile("s_waitcnt lgkmcnt(0)" ::: "memory");
    __builtin_amdgcn_sched_barrier(0);
    bf16x8 pa[2];
    {
      int ba0 = (lr * 128 + lg * 16) ^ ((lr & 7) << 4);
      int ba1 = (lr * 128 + 64 + lg * 16) ^ ((lr & 7) << 4);
      pa[0] = *(const bf16x8*)((char*)pw + ba0);
      pa[1] = *(const bf16x8*)((char*)pw + ba1);
    }
    // PV: o[dt] += P(16x64) @ V(64x16)
#pragma unroll
    for (int dt = 0; dt < 4; dt++) {
      bf16x8 vf0 = *(const bf16x8*)(Vh + (dt * 16 + lr) * S_LEN + kv + lg * 8);
      bf16x8 vf1 = *(const bf16x8*)(Vh + (dt * 16 + lr) * S_LEN + kv + 32 + lg * 8);
      o[dt] = __builtin_amdgcn_mfma_f32_16x16x32_bf16(pa[0], vf0, o[dt], 0, 0, 0);
      o[dt] = __builtin_amdgcn_mfma_f32_16x16x32_bf16(pa[1], vf1, o[dt], 0, 0, 0);
    }
  }
  // epilogue: out[b][s][h*64+d] = o/l
  int h = n >> 2, b = n & 3;
#pragma unroll
  for (int r = 0; r < 4; r++) {
    float inv = 1.0f / lrow[r];
    int s = qw + lg * 4 + r;
    float* op = out + (size_t)(b * S_LEN + s) * D_MODEL + h * DEP + lr;
    op[0]  = o[0][r] * inv;
    op[16] = o[1][r] * inv;
    op[32] = o[2][r] * inv;
    op[48] = o[3][r] * inv;
  }
}

extern "C" void kernel_launch(void* const* d_in, const int* in_sizes, int n_in,
                              void* d_out, int out_size, void* d_ws, size_t ws_size,
                              hipStream_t stream) {
  const float* q  = (const float*)d_in[0];
  const float* k  = (const float*)d_in[1];
  const float* v  = (const float*)d_in[2];
  const float* Wq = (const float*)d_in[3];
  const float* bq = (const float*)d_in[4];
  const float* Wk = (const float*)d_in[5];
  const float* bk = (const float*)d_in[6];
  const float* Wv = (const float*)d_in[7];
  const float* bv = (const float*)d_in[8];
  float* out = (float*)d_out;

  const size_t XN = (size_t)M_ROWS * D_MODEL;      // 8388608
  const size_t WN = (size_t)D_MODEL * D_MODEL;     // 1048576
  const size_t HN = (size_t)NHEADS * S_LEN * DEP;  // 8388608

  unsigned short* qb  = (unsigned short*)d_ws;
  unsigned short* kb  = qb + XN;
  unsigned short* vb  = kb + XN;
  unsigned short* Wqt = vb + XN;
  unsigned short* Wkt = Wqt + WN;
  unsigned short* Wvt = Wkt + WN;
  unsigned short* Qh  = Wvt + WN;
  unsigned short* Kh  = Qh + HN;
  unsigned short* Vh  = Kh + HN;
  unsigned short* Vts = Vh + HN;

  // 1) convert inputs to bf16
  int n4 = (int)(XN / 4);
  cvt_f32_bf16<<<n4 / 256, 256, 0, stream>>>(q, qb, n4);
  cvt_f32_bf16<<<n4 / 256, 256, 0, stream>>>(k, kb, n4);
  cvt_f32_bf16<<<n4 / 256, 256, 0, stream>>>(v, vb, n4);

  // 2) transpose-convert weights
  dim3 wg(32, 32);
  transpose_cvt_w<<<wg, 256, 0, stream>>>(Wq, Wqt);
  transpose_cvt_w<<<wg, 256, 0, stream>>>(Wk, Wkt);
  transpose_cvt_w<<<wg, 256, 0, stream>>>(Wv, Wvt);

  // 3) projections -> head-major bf16 (Q pre-scaled by 1/sqrt(64))
  dim3 gg(M_ROWS / 128, D_MODEL / 128);
  gemm_qkv<<<gg, 256, 0, stream>>>(qb, Wqt, bq, Qh, 0.125f);
  gemm_qkv<<<gg, 256, 0, stream>>>(kb, Wkt, bk, Kh, 1.0f);
  gemm_qkv<<<gg, 256, 0, stream>>>(vb, Wvt, bv, Vh, 1.0f);

  // 4) V -> Vt (n,d,s)
  dim3 tv(S_LEN / 64, NHEADS);
  transpose_v<<<tv, 256, 0, stream>>>(Vh, Vts);

  // 5) causal flash attention
  dim3 ag(S_LEN / 64, NHEADS);
  attn_fwd<<<ag, 256, 0, stream>>>(Qh, Kh, Vts, out);
}

// Round 3
// 250.100 us; speedup vs baseline: 2.2947x; 2.2947x over previous
//
#include <hip/hip_runtime.h>

#define S_LEN   2048
#define D_MODEL 1024
#define NB      4
#define NH      16
#define DEP     64
#define NHEADS  64      // NH*NB
#define M_ROWS  8192    // NB*S_LEN

typedef __bf16 bf16_t;
typedef bf16_t bf16x8 __attribute__((ext_vector_type(8)));
typedef bf16_t bf16x2 __attribute__((ext_vector_type(2)));
typedef float  f32x4  __attribute__((ext_vector_type(4)));
typedef float  f32x16 __attribute__((ext_vector_type(16)));
typedef unsigned int u32x2 __attribute__((ext_vector_type(2)));

#define LOG2E 1.4426950408889634f

#if __has_builtin(__builtin_amdgcn_exp2f)
  #define EXP2(x) __builtin_amdgcn_exp2f(x)
#else
  #define EXP2(x) exp2f(x)
#endif

#define GLOBAL_AS(p) ((const __attribute__((address_space(1))) void*)(p))
#define LDS_AS(p)    ((__attribute__((address_space(3))) void*)(p))

__device__ __forceinline__ unsigned short bf16r(float f) {
  unsigned u = __builtin_bit_cast(unsigned, f);
  u = (u + 0x7FFFu + ((u >> 16) & 1u)) >> 16;
  return (unsigned short)u;
}

// pack two f32 -> 2xbf16 in one u32 (compiler emits v_cvt_pk_bf16_f32)
__device__ __forceinline__ unsigned pkbf(float lo, float hi) {
  bf16x2 t;
  t[0] = (bf16_t)lo;
  t[1] = (bf16_t)hi;
  return __builtin_bit_cast(unsigned, t);
}

// ---------------- fp32 -> bf16 convert (linear) ----------------
__global__ __launch_bounds__(256) void cvt_f32_bf16(
    const float* __restrict__ in, unsigned short* __restrict__ out, int n4) {
  int i = blockIdx.x * 256 + threadIdx.x;
  if (i >= n4) return;
  float4 v = reinterpret_cast<const float4*>(in)[i];
  ushort4 o;
  o.x = bf16r(v.x); o.y = bf16r(v.y); o.z = bf16r(v.z); o.w = bf16r(v.w);
  reinterpret_cast<ushort4*>(out)[i] = o;
}

// ---------------- W (K,N) fp32 -> Wt (N,K) bf16 ----------------
__global__ __launch_bounds__(256) void transpose_cvt_w(
    const float* __restrict__ in, unsigned short* __restrict__ out) {
  __shared__ unsigned short tile[32][33];
  int bx = blockIdx.x * 32;  // n base
  int by = blockIdx.y * 32;  // k base
  int tx = threadIdx.x & 31, ty = threadIdx.x >> 5; // 32x8
  for (int i = ty; i < 32; i += 8)
    tile[i][tx] = bf16r(in[(by + i) * D_MODEL + bx + tx]);
  __syncthreads();
  for (int i = ty; i < 32; i += 8)
    out[(size_t)(bx + i) * D_MODEL + by + tx] = tile[tx][i];
}

// ---------------- bf16 GEMM: (8192,1024) @ W(k,n) -> head-major bf16 ------
__global__ __launch_bounds__(256) void gemm_qkv(
    const unsigned short* __restrict__ A,
    const unsigned short* __restrict__ Bt,
    const float* __restrict__ bias,
    unsigned short* __restrict__ out,
    float scale) {
  __shared__ __align__(16) unsigned short Asb[128 * 32];
  __shared__ __align__(16) unsigned short Bsb[128 * 32];
  int tid = threadIdx.x, lane = tid & 63, wid = tid >> 6;
  int lr = lane & 15, lg = lane >> 4;
  int m0 = blockIdx.x * 128, n0 = blockIdx.y * 128;
  int wr = wid >> 1, wc = wid & 1;
  f32x4 acc[4][4] = {};
  for (int kt = 0; kt < D_MODEL / 32; kt++) {
    int k0 = kt * 32;
#pragma unroll
    for (int i = 0; i < 2; i++) {
      int chunk = i * 256 + wid * 64 + lane;      // 512 chunks of 8 elts
      int r = chunk >> 2, c = (chunk & 3) * 8;
      __builtin_amdgcn_global_load_lds(
          GLOBAL_AS(A + (size_t)(m0 + r) * D_MODEL + k0 + c),
          LDS_AS(Asb + (size_t)(i * 256 + wid * 64) * 8), 16, 0, 0);
      __builtin_amdgcn_global_load_lds(
          GLOBAL_AS(Bt + (size_t)(n0 + r) * D_MODEL + k0 + c),
          LDS_AS(Bsb + (size_t)(i * 256 + wid * 64) * 8), 16, 0, 0);
    }
    __syncthreads();
    bf16x8 af[4], bfr[4];
#pragma unroll
    for (int mi = 0; mi < 4; mi++)
      af[mi] = *(const bf16x8*)(Asb + (wr * 64 + mi * 16 + lr) * 32 + lg * 8);
#pragma unroll
    for (int ni = 0; ni < 4; ni++)
      bfr[ni] = *(const bf16x8*)(Bsb + (wc * 64 + ni * 16 + lr) * 32 + lg * 8);
#pragma unroll
    for (int mi = 0; mi < 4; mi++)
#pragma unroll
      for (int ni = 0; ni < 4; ni++)
        acc[mi][ni] = __builtin_amdgcn_mfma_f32_16x16x32_bf16(
            af[mi], bfr[ni], acc[mi][ni], 0, 0, 0);
    __syncthreads();
  }
#pragma unroll
  for (int mi = 0; mi < 4; mi++) {
#pragma unroll
    for (int ni = 0; ni < 4; ni++) {
      int col = n0 + wc * 64 + ni * 16 + lr;
      float bv = bias[col];
      int h = col >> 6, d = col & 63;
#pragma unroll
      for (int r = 0; r < 4; r++) {
        int row = m0 + wr * 64 + mi * 16 + lg * 4 + r;
        int b = row >> 11, s = row & (S_LEN - 1);
        float v = (acc[mi][ni][r] + bv) * scale;
        out[((size_t)(h * NB + b) * S_LEN + s) * DEP + d] = bf16r(v);
      }
    }
  }
}

// ---------------- V head-major (n,s,d) -> Vt (n,d,s) ----------------
__global__ __launch_bounds__(256) void transpose_v(
    const unsigned short* __restrict__ in, unsigned short* __restrict__ out) {
  __shared__ unsigned short t[64][65];
  int n = blockIdx.y, s0 = blockIdx.x * 64;
  for (int i = 0; i < 16; i++) {
    int idx = i * 256 + threadIdx.x;
    int r = idx >> 6, c = idx & 63;
    t[r][c] = in[((size_t)n * S_LEN + s0 + r) * DEP + c];
  }
  __syncthreads();
  for (int i = 0; i < 16; i++) {
    int idx = i * 256 + threadIdx.x;
    int d = idx >> 6, c = idx & 63;
    out[((size_t)n * DEP + d) * S_LEN + s0 + c] = t[c][d];
  }
}

// ---------------- causal flash attention, swapped-operand 32x32 ----------
// Q,K head-major (64,2048,64) bf16 (Q pre-scaled by 0.125), Vt (64,64,2048).
// Each wave independently owns q-tiles j and 63-j (32 rows each): exactly 33
// KV-tile iterations per wave. S^T = mfma(K, Q^T): lane holds a full P-row
// (q = lane&31, kv = crow(r,hi) = (r&3)+8*(r>>2)+4*hi). O^T = mfma(V^T, P^T).
// Softmax in registers; cross-half combine via __shfl_xor(32); P^T packing
// via wave-private XOR-swizzled LDS (the R1-verified pattern, no permlane).
__global__ __launch_bounds__(256, 2) void attn_fwd(
    const unsigned short* __restrict__ Q,
    const unsigned short* __restrict__ K,
    const unsigned short* __restrict__ Vt,
    float* __restrict__ out) {
  __shared__ float olds[4][32 * 65];
  __shared__ __align__(16) unsigned short plds[4][32 * 64];  // 4KB per wave
  const int tid = threadIdx.x, lane = tid & 63, wid = tid >> 6;
  const int l31 = lane & 31, hi = lane >> 5;
  const int n = blockIdx.y, h = n >> 2, b = n & 3;
  const int jj = blockIdx.x * 4 + wid;   // 0..31
  const unsigned short* Qh = Q + (size_t)n * S_LEN * DEP;
  const unsigned short* Kh = K + (size_t)n * S_LEN * DEP;
  const unsigned short* Vh = Vt + (size_t)n * DEP * S_LEN;
  float* ow = &olds[wid][0];
  char* pw = (char*)&plds[wid][0];
  const int swz = (l31 & 7) << 4;

  for (int pass = 0; pass < 2; pass++) {
    const int j = pass ? (63 - jj) : jj;
    const int q0 = j * 32;
    const int qrow = q0 + l31;

    bf16x8 qf[4];
#pragma unroll
    for (int ds = 0; ds < 4; ds++)
      qf[ds] = *(const bf16x8*)(Qh + (size_t)qrow * DEP + ds * 16 + hi * 8);

    f32x16 o0 = {}, o1 = {};
    float m = -3.0e38f, l = 0.f;
    const int nt = (j >> 1) + 1;

    for (int t = 0; t < nt; t++) {
      const int kvb = t * 64;
      f32x16 p0 = {}, p1 = {};
#pragma unroll
      for (int ds = 0; ds < 4; ds++) {
        bf16x8 kf0 = *(const bf16x8*)(Kh + (size_t)(kvb + l31) * DEP + ds * 16 + hi * 8);
        bf16x8 kf1 = *(const bf16x8*)(Kh + (size_t)(kvb + 32 + l31) * DEP + ds * 16 + hi * 8);
        p0 = __builtin_amdgcn_mfma_f32_32x32x16_bf16(kf0, qf[ds], p0, 0, 0, 0);
        p1 = __builtin_amdgcn_mfma_f32_32x32x16_bf16(kf1, qf[ds], p1, 0, 0, 0);
      }
      if (t == nt - 1) {  // diagonal tile: causal mask (kv > q -> -inf)
#pragma unroll
        for (int r = 0; r < 16; r++) {
          int kvr = kvb + (r & 3) + 8 * (r >> 2) + 4 * hi;
          if (kvr > qrow)      p0[r] = -3.0e38f;
          if (kvr + 32 > qrow) p1[r] = -3.0e38f;
        }
      }
      // ---- in-register online softmax ----
      f32x16 tr;
#pragma unroll
      for (int r = 0; r < 16; r++) tr[r] = fmaxf(p0[r], p1[r]);
#pragma unroll
      for (int s = 8; s >= 1; s >>= 1)
#pragma unroll
        for (int r = 0; r < 16; r++)
          if (r < s) tr[r] = fmaxf(tr[r], tr[r + s]);
      float mx = tr[0];
      mx = fmaxf(mx, __shfl_xor(mx, 32));
      const float mnew = fmaxf(m, mx);
      const float alpha = EXP2((m - mnew) * LOG2E);
      m = mnew;
#pragma unroll
      for (int r = 0; r < 16; r++) {
        p0[r] = EXP2((p0[r] - m) * LOG2E);
        p1[r] = EXP2((p1[r] - m) * LOG2E);
      }
      f32x16 sm;
#pragma unroll
      for (int r = 0; r < 16; r++) sm[r] = p0[r] + p1[r];
#pragma unroll
      for (int s = 8; s >= 1; s >>= 1)
#pragma unroll
        for (int r = 0; r < 16; r++)
          if (r < s) sm[r] = sm[r] + sm[r + s];
      float ss = sm[0];
      ss += __shfl_xor(ss, 32);
      l = l * alpha + ss;
#pragma unroll
      for (int r = 0; r < 16; r++) { o0[r] *= alpha; o1[r] *= alpha; }

      // ---- P^T -> wave-private LDS (XOR-swizzled), R1-verified pattern ----
      // lane holds q=l31 column; kv(r=4a+i) = i + 8a + 4hi (+32 for p1).
#pragma unroll
      for (int h2 = 0; h2 < 2; h2++) {
        const f32x16& p = h2 ? p1 : p0;
#pragma unroll
        for (int a = 0; a < 4; a++) {
          u32x2 w;
          w[0] = pkbf(p[4 * a + 0], p[4 * a + 1]);
          w[1] = pkbf(p[4 * a + 2], p[4 * a + 3]);
          int ba = (l31 * 128 + h2 * 64 + a * 16 + hi * 8) ^ swz;
          *(u32x2*)(pw + ba) = w;
        }
      }
      // read back as B-frags: element j of pa[ks] = P[q=l31][kv=ks*16+hi*8+j]
      bf16x8 pa[4];
#pragma unroll
      for (int ks = 0; ks < 4; ks++) {
        int ba = (l31 * 128 + ks * 32 + hi * 16) ^ swz;
        pa[ks] = *(const bf16x8*)(pw + ba);
      }
      // ---- O^T += V^T @ P^T ----
#pragma unroll
      for (int ks = 0; ks < 4; ks++) {
        bf16x8 vf0 = *(const bf16x8*)(Vh + (size_t)(l31) * S_LEN + kvb + ks * 16 + hi * 8);
        bf16x8 vf1 = *(const bf16x8*)(Vh + (size_t)(32 + l31) * S_LEN + kvb + ks * 16 + hi * 8);
        o0 = __builtin_amdgcn_mfma_f32_32x32x16_bf16(vf0, pa[ks], o0, 0, 0, 0);
        o1 = __builtin_amdgcn_mfma_f32_32x32x16_bf16(vf1, pa[ks], o1, 0, 0, 0);
      }
    }

    // ---- epilogue: O^T -> LDS (stride 65, conflict-free) -> coalesced ----
    const float inv = 1.0f / l;
#pragma unroll
    for (int r = 0; r < 16; r++) {
      int d0 = (r & 3) + 8 * (r >> 2) + 4 * hi;
      ow[l31 * 65 + d0]      = o0[r] * inv;
      ow[l31 * 65 + 32 + d0] = o1[r] * inv;
    }
#pragma unroll
    for (int i = 0; i < 8; i++) {
      int idx = i * 64 + lane;   // 0..511
      int row = idx >> 4;        // 0..31
      int c4 = idx & 15;         // col = c4*4
      float4 vv;
      vv.x = ow[row * 65 + c4 * 4 + 0];
      vv.y = ow[row * 65 + c4 * 4 + 1];
      vv.z = ow[row * 65 + c4 * 4 + 2];
      vv.w = ow[row * 65 + c4 * 4 + 3];
      *(float4*)(out + (size_t)(b * S_LEN + q0 + row) * D_MODEL + h * DEP + c4 * 4) = vv;
    }
  }
}

extern "C" void kernel_launch(void* const* d_in, const int* in_sizes, int n_in,
                              void* d_out, int out_size, void* d_ws, size_t ws_size,
                              hipStream_t stream) {
  const float* q  = (const float*)d_in[0];
  const float* k  = (const float*)d_in[1];
  const float* v  = (const float*)d_in[2];
  const float* Wq = (const float*)d_in[3];
  const float* bq = (const float*)d_in[4];
  const float* Wk = (const float*)d_in[5];
  const float* bk = (const float*)d_in[6];
  const float* Wv = (const float*)d_in[7];
  const float* bv = (const float*)d_in[8];
  float* out = (float*)d_out;

  const size_t XN = (size_t)M_ROWS * D_MODEL;      // 8388608
  const size_t WN = (size_t)D_MODEL * D_MODEL;     // 1048576
  const size_t HN = (size_t)NHEADS * S_LEN * DEP;  // 8388608

  unsigned short* qb  = (unsigned short*)d_ws;
  unsigned short* kb  = qb + XN;
  unsigned short* vb  = kb + XN;
  unsigned short* Wqt = vb + XN;
  unsigned short* Wkt = Wqt + WN;
  unsigned short* Wvt = Wkt + WN;
  unsigned short* Qh  = Wvt + WN;
  unsigned short* Kh  = Qh + HN;
  unsigned short* Vh  = Kh + HN;
  unsigned short* Vts = Vh + HN;

  int n4 = (int)(XN / 4);
  cvt_f32_bf16<<<n4 / 256, 256, 0, stream>>>(q, qb, n4);
  cvt_f32_bf16<<<n4 / 256, 256, 0, stream>>>(k, kb, n4);
  cvt_f32_bf16<<<n4 / 256, 256, 0, stream>>>(v, vb, n4);

  dim3 wg(32, 32);
  transpose_cvt_w<<<wg, 256, 0, stream>>>(Wq, Wqt);
  transpose_cvt_w<<<wg, 256, 0, stream>>>(Wk, Wkt);
  transpose_cvt_w<<<wg, 256, 0, stream>>>(Wv, Wvt);

  dim3 gg(M_ROWS / 128, D_MODEL / 128);
  gemm_qkv<<<gg, 256, 0, stream>>>(qb, Wqt, bq, Qh, 0.125f);
  gemm_qkv<<<gg, 256, 0, stream>>>(kb, Wkt, bk, Kh, 1.0f);
  gemm_qkv<<<gg, 256, 0, stream>>>(vb, Wvt, bv, Vh, 1.0f);

  dim3 tv(S_LEN / 64, NHEADS);
  transpose_v<<<tv, 256, 0, stream>>>(Vh, Vts);

  dim3 ag(8, NHEADS);
  attn_fwd<<<ag, 256, 0, stream>>>(Qh, Kh, Vts, out);
}

// Round 4
// 229.799 us; speedup vs baseline: 2.4974x; 1.0883x over previous
//
#include <hip/hip_runtime.h>

#define S_LEN   2048
#define D_MODEL 1024
#define NB      4
#define NH      16
#define DEP     64
#define NHEADS  64      // NH*NB
#define M_ROWS  8192    // NB*S_LEN

typedef __bf16 bf16_t;
typedef bf16_t bf16x8 __attribute__((ext_vector_type(8)));
typedef bf16_t bf16x2 __attribute__((ext_vector_type(2)));
typedef float  f32x4  __attribute__((ext_vector_type(4)));
typedef float  f32x16 __attribute__((ext_vector_type(16)));
typedef unsigned int u32x2 __attribute__((ext_vector_type(2)));

#define LOG2E 1.4426950408889634f

#if __has_builtin(__builtin_amdgcn_exp2f)
  #define EXP2(x) __builtin_amdgcn_exp2f(x)
#else
  #define EXP2(x) exp2f(x)
#endif

#define GLOBAL_AS(p) ((const __attribute__((address_space(1))) void*)(p))
#define LDS_AS(p)    ((__attribute__((address_space(3))) void*)(p))

__device__ __forceinline__ unsigned short bf16r(float f) {
  unsigned u = __builtin_bit_cast(unsigned, f);
  u = (u + 0x7FFFu + ((u >> 16) & 1u)) >> 16;
  return (unsigned short)u;
}

__device__ __forceinline__ unsigned pkbf(float lo, float hi) {
  bf16x2 t;
  t[0] = (bf16_t)lo;
  t[1] = (bf16_t)hi;
  return __builtin_bit_cast(unsigned, t);
}

// ---------------- fp32 -> bf16 convert, 3 tensors in one launch ----------
__global__ __launch_bounds__(256) void cvt3_f32_bf16(
    const float* __restrict__ q, const float* __restrict__ k,
    const float* __restrict__ v,
    unsigned short* __restrict__ qo, unsigned short* __restrict__ ko,
    unsigned short* __restrict__ vo, int n4) {
  int z = blockIdx.y;
  const float* in = (z == 0) ? q : (z == 1) ? k : v;
  unsigned short* out = (z == 0) ? qo : (z == 1) ? ko : vo;
  int i = blockIdx.x * 256 + threadIdx.x;
  if (i >= n4) return;
  float4 val = reinterpret_cast<const float4*>(in)[i];
  ushort4 o;
  o.x = bf16r(val.x); o.y = bf16r(val.y); o.z = bf16r(val.z); o.w = bf16r(val.w);
  reinterpret_cast<ushort4*>(out)[i] = o;
}

// ---------------- W (K,N) fp32 -> Wt (N,K) bf16, 3 in one launch ---------
__global__ __launch_bounds__(256) void transpose_cvt_w3(
    const float* __restrict__ Wq, const float* __restrict__ Wk,
    const float* __restrict__ Wv,
    unsigned short* __restrict__ oq, unsigned short* __restrict__ ok,
    unsigned short* __restrict__ ov) {
  __shared__ unsigned short tile[32][33];
  int z = blockIdx.z;
  const float* in = (z == 0) ? Wq : (z == 1) ? Wk : Wv;
  unsigned short* out = (z == 0) ? oq : (z == 1) ? ok : ov;
  int bx = blockIdx.x * 32;  // n base
  int by = blockIdx.y * 32;  // k base
  int tx = threadIdx.x & 31, ty = threadIdx.x >> 5; // 32x8
  for (int i = ty; i < 32; i += 8)
    tile[i][tx] = bf16r(in[(by + i) * D_MODEL + bx + tx]);
  __syncthreads();
  for (int i = ty; i < 32; i += 8)
    out[(size_t)(bx + i) * D_MODEL + by + tx] = tile[tx][i];
}

// ---------------- bf16 GEMM x3: (8192,1024) @ W -> head-major bf16 -------
__global__ __launch_bounds__(256) void gemm_qkv3(
    const unsigned short* __restrict__ Aq, const unsigned short* __restrict__ Ak,
    const unsigned short* __restrict__ Av,
    const unsigned short* __restrict__ Btq, const unsigned short* __restrict__ Btk,
    const unsigned short* __restrict__ Btv,
    const float* __restrict__ bq, const float* __restrict__ bk,
    const float* __restrict__ bv,
    unsigned short* __restrict__ oq, unsigned short* __restrict__ ok,
    unsigned short* __restrict__ ov) {
  __shared__ __align__(16) unsigned short Asb[128 * 32];
  __shared__ __align__(16) unsigned short Bsb[128 * 32];
  int z = blockIdx.z;
  const unsigned short* A  = (z == 0) ? Aq  : (z == 1) ? Ak  : Av;
  const unsigned short* Bt = (z == 0) ? Btq : (z == 1) ? Btk : Btv;
  const float* bias        = (z == 0) ? bq  : (z == 1) ? bk  : bv;
  unsigned short* out      = (z == 0) ? oq  : (z == 1) ? ok  : ov;
  const float scale        = (z == 0) ? 0.125f : 1.0f;
  int tid = threadIdx.x, lane = tid & 63, wid = tid >> 6;
  int lr = lane & 15, lg = lane >> 4;
  int m0 = blockIdx.x * 128, n0 = blockIdx.y * 128;
  int wr = wid >> 1, wc = wid & 1;
  f32x4 acc[4][4] = {};
  for (int kt = 0; kt < D_MODEL / 32; kt++) {
    int k0 = kt * 32;
#pragma unroll
    for (int i = 0; i < 2; i++) {
      int chunk = i * 256 + wid * 64 + lane;      // 512 chunks of 8 elts
      int r = chunk >> 2, c = (chunk & 3) * 8;
      __builtin_amdgcn_global_load_lds(
          GLOBAL_AS(A + (size_t)(m0 + r) * D_MODEL + k0 + c),
          LDS_AS(Asb + (size_t)(i * 256 + wid * 64) * 8), 16, 0, 0);
      __builtin_amdgcn_global_load_lds(
          GLOBAL_AS(Bt + (size_t)(n0 + r) * D_MODEL + k0 + c),
          LDS_AS(Bsb + (size_t)(i * 256 + wid * 64) * 8), 16, 0, 0);
    }
    __syncthreads();
    bf16x8 af[4], bfr[4];
#pragma unroll
    for (int mi = 0; mi < 4; mi++)
      af[mi] = *(const bf16x8*)(Asb + (wr * 64 + mi * 16 + lr) * 32 + lg * 8);
#pragma unroll
    for (int ni = 0; ni < 4; ni++)
      bfr[ni] = *(const bf16x8*)(Bsb + (wc * 64 + ni * 16 + lr) * 32 + lg * 8);
#pragma unroll
    for (int mi = 0; mi < 4; mi++)
#pragma unroll
      for (int ni = 0; ni < 4; ni++)
        acc[mi][ni] = __builtin_amdgcn_mfma_f32_16x16x32_bf16(
            af[mi], bfr[ni], acc[mi][ni], 0, 0, 0);
    __syncthreads();
  }
#pragma unroll
  for (int mi = 0; mi < 4; mi++) {
#pragma unroll
    for (int ni = 0; ni < 4; ni++) {
      int col = n0 + wc * 64 + ni * 16 + lr;
      float bvv = bias[col];
      int h = col >> 6, d = col & 63;
#pragma unroll
      for (int r = 0; r < 4; r++) {
        int row = m0 + wr * 64 + mi * 16 + lg * 4 + r;
        int b = row >> 11, s = row & (S_LEN - 1);
        float val = (acc[mi][ni][r] + bvv) * scale;
        out[((size_t)(h * NB + b) * S_LEN + s) * DEP + d] = bf16r(val);
      }
    }
  }
}

// ---------------- V head-major (n,s,d) -> Vt (n,d,s) ----------------
__global__ __launch_bounds__(256) void transpose_v(
    const unsigned short* __restrict__ in, unsigned short* __restrict__ out) {
  __shared__ unsigned short t[64][65];
  int n = blockIdx.y, s0 = blockIdx.x * 64;
  for (int i = 0; i < 16; i++) {
    int idx = i * 256 + threadIdx.x;
    int r = idx >> 6, c = idx & 63;
    t[r][c] = in[((size_t)n * S_LEN + s0 + r) * DEP + c];
  }
  __syncthreads();
  for (int i = 0; i < 16; i++) {
    int idx = i * 256 + threadIdx.x;
    int d = idx >> 6, c = idx & 63;
    out[((size_t)n * DEP + d) * S_LEN + s0 + c] = t[c][d];
  }
}

// ---------------- causal flash attention, swapped-operand 32x32 ----------
// Q,K head-major (64,2048,64) bf16 (Q pre-scaled 0.125), Vt (64,64,2048).
// Block decode: xcd = id&7 owns heads xcd*8..+7 (per-XCD KV working set
// ~4MB -> L2-resident). Wave handles q-tile pair (j, 63-j): exactly 17
// KVBLK=128 iterations each. S^T = mfma(K, Q^T): lane holds P-row
// (q=lane&31, kv = c*32 + (r&3)+8*(r>>2)+4*hi). O^T = mfma(V^T, P^T).
__global__ __launch_bounds__(256, 2) void attn_fwd(
    const unsigned short* __restrict__ Q,
    const unsigned short* __restrict__ K,
    const unsigned short* __restrict__ Vt,
    float* __restrict__ out) {
  __shared__ __align__(16) char wmem[4][8448];   // P^T (8KB) / epilogue (8.32KB)
  const int tid = threadIdx.x, lane = tid & 63, wid = tid >> 6;
  const int l31 = lane & 31, hi = lane >> 5;
  const int id = blockIdx.x;
  const int xcd = id & 7, qq = id >> 3;          // qq 0..63
  const int n = xcd * 8 + (qq & 7);              // head-batch index
  const int jj = (qq >> 3) * 4 + wid;            // 0..31
  const int h = n >> 2, b = n & 3;
  const unsigned short* Qh = Q + (size_t)n * S_LEN * DEP;
  const unsigned short* Kh = K + (size_t)n * S_LEN * DEP;
  const unsigned short* Vh = Vt + (size_t)n * DEP * S_LEN;
  char* pw = &wmem[wid][0];
  float* ow = (float*)&wmem[wid][0];
  const int swz = (l31 & 7) << 4;

  for (int pass = 0; pass < 2; pass++) {
    const int j = pass ? (63 - jj) : jj;
    const int q0 = j * 32;
    const int qrow = q0 + l31;

    bf16x8 qf[4];
#pragma unroll
    for (int ds = 0; ds < 4; ds++)
      qf[ds] = *(const bf16x8*)(Qh + (size_t)qrow * DEP + ds * 16 + hi * 8);

    f32x16 o0 = {}, o1 = {};
    float m = -3.0e38f, l = 0.f;
    const int nt = (j >> 2) + 1;                 // KV tiles of 128

    for (int t = 0; t < nt; t++) {
      const int kvb = t * 128;
      f32x16 p[4] = {{}, {}, {}, {}};
      __builtin_amdgcn_s_setprio(1);
#pragma unroll
      for (int ds = 0; ds < 4; ds++) {
        bf16x8 kf[4];
#pragma unroll
        for (int c = 0; c < 4; c++)
          kf[c] = *(const bf16x8*)(Kh + (size_t)(kvb + c * 32 + l31) * DEP + ds * 16 + hi * 8);
#pragma unroll
        for (int c = 0; c < 4; c++)
          p[c] = __builtin_amdgcn_mfma_f32_32x32x16_bf16(kf[c], qf[ds], p[c], 0, 0, 0);
      }
      __builtin_amdgcn_s_setprio(0);
      if (t == nt - 1) {  // diagonal tile: causal mask (kv > q -> -inf)
#pragma unroll
        for (int c = 0; c < 4; c++)
#pragma unroll
          for (int r = 0; r < 16; r++) {
            int kvr = kvb + c * 32 + (r & 3) + 8 * (r >> 2) + 4 * hi;
            if (kvr > qrow) p[c][r] = -3.0e38f;
          }
      }
      // ---- in-register online softmax (row = q = l31) ----
      f32x16 tr;
#pragma unroll
      for (int r = 0; r < 16; r++)
        tr[r] = fmaxf(fmaxf(p[0][r], p[1][r]), fmaxf(p[2][r], p[3][r]));
#pragma unroll
      for (int s = 8; s >= 1; s >>= 1)
#pragma unroll
        for (int r = 0; r < 16; r++)
          if (r < s) tr[r] = fmaxf(tr[r], tr[r + s]);
      float mx = tr[0];
      mx = fmaxf(mx, __shfl_xor(mx, 32));
      const float mnew = fmaxf(m, mx);
      const float alpha = EXP2((m - mnew) * LOG2E);
      m = mnew;
#pragma unroll
      for (int c = 0; c < 4; c++)
#pragma unroll
        for (int r = 0; r < 16; r++)
          p[c][r] = EXP2((p[c][r] - m) * LOG2E);
      f32x16 sm;
#pragma unroll
      for (int r = 0; r < 16; r++)
        sm[r] = (p[0][r] + p[1][r]) + (p[2][r] + p[3][r]);
#pragma unroll
      for (int s = 8; s >= 1; s >>= 1)
#pragma unroll
        for (int r = 0; r < 16; r++)
          if (r < s) sm[r] = sm[r] + sm[r + s];
      float ss = sm[0];
      ss += __shfl_xor(ss, 32);
      l = l * alpha + ss;
#pragma unroll
      for (int r = 0; r < 16; r++) { o0[r] *= alpha; o1[r] *= alpha; }

      // ---- P^T -> wave-private LDS (XOR-swizzled), row q stride 256B ----
#pragma unroll
      for (int c = 0; c < 4; c++)
#pragma unroll
        for (int a = 0; a < 4; a++) {
          u32x2 w;
          w[0] = pkbf(p[c][4 * a + 0], p[c][4 * a + 1]);
          w[1] = pkbf(p[c][4 * a + 2], p[c][4 * a + 3]);
          int ba = (l31 * 256 + c * 64 + a * 16 + hi * 8) ^ swz;
          *(u32x2*)(pw + ba) = w;
        }
      asm volatile("s_waitcnt lgkmcnt(0)" ::: "memory");
      __builtin_amdgcn_sched_barrier(0);
      bf16x8 pa[8];
#pragma unroll
      for (int ks = 0; ks < 8; ks++) {
        int ba = (l31 * 256 + ks * 32 + hi * 16) ^ swz;
        pa[ks] = *(const bf16x8*)(pw + ba);
      }
      // ---- O^T += V^T @ P^T ----
      __builtin_amdgcn_s_setprio(1);
#pragma unroll
      for (int ks = 0; ks < 8; ks++) {
        bf16x8 vf0 = *(const bf16x8*)(Vh + (size_t)(l31) * S_LEN + kvb + ks * 16 + hi * 8);
        bf16x8 vf1 = *(const bf16x8*)(Vh + (size_t)(32 + l31) * S_LEN + kvb + ks * 16 + hi * 8);
        o0 = __builtin_amdgcn_mfma_f32_32x32x16_bf16(vf0, pa[ks], o0, 0, 0, 0);
        o1 = __builtin_amdgcn_mfma_f32_32x32x16_bf16(vf1, pa[ks], o1, 0, 0, 0);
      }
      __builtin_amdgcn_s_setprio(0);
    }

    // ---- epilogue: O^T -> LDS (stride 65, conflict-free) -> coalesced ----
    const float inv = 1.0f / l;
#pragma unroll
    for (int r = 0; r < 16; r++) {
      int d0 = (r & 3) + 8 * (r >> 2) + 4 * hi;
      ow[l31 * 65 + d0]      = o0[r] * inv;
      ow[l31 * 65 + 32 + d0] = o1[r] * inv;
    }
    asm volatile("s_waitcnt lgkmcnt(0)" ::: "memory");
    __builtin_amdgcn_sched_barrier(0);
#pragma unroll
    for (int i = 0; i < 8; i++) {
      int idx = i * 64 + lane;   // 0..511
      int row = idx >> 4;        // 0..31
      int c4 = idx & 15;         // col = c4*4
      float4 vv;
      vv.x = ow[row * 65 + c4 * 4 + 0];
      vv.y = ow[row * 65 + c4 * 4 + 1];
      vv.z = ow[row * 65 + c4 * 4 + 2];
      vv.w = ow[row * 65 + c4 * 4 + 3];
      *(float4*)(out + (size_t)(b * S_LEN + q0 + row) * D_MODEL + h * DEP + c4 * 4) = vv;
    }
  }
}

extern "C" void kernel_launch(void* const* d_in, const int* in_sizes, int n_in,
                              void* d_out, int out_size, void* d_ws, size_t ws_size,
                              hipStream_t stream) {
  const float* q  = (const float*)d_in[0];
  const float* k  = (const float*)d_in[1];
  const float* v  = (const float*)d_in[2];
  const float* Wq = (const float*)d_in[3];
  const float* bq = (const float*)d_in[4];
  const float* Wk = (const float*)d_in[5];
  const float* bk = (const float*)d_in[6];
  const float* Wv = (const float*)d_in[7];
  const float* bv = (const float*)d_in[8];
  float* out = (float*)d_out;

  const size_t XN = (size_t)M_ROWS * D_MODEL;      // 8388608
  const size_t WN = (size_t)D_MODEL * D_MODEL;     // 1048576
  const size_t HN = (size_t)NHEADS * S_LEN * DEP;  // 8388608

  unsigned short* qb  = (unsigned short*)d_ws;
  unsigned short* kb  = qb + XN;
  unsigned short* vb  = kb + XN;
  unsigned short* Wqt = vb + XN;
  unsigned short* Wkt = Wqt + WN;
  unsigned short* Wvt = Wkt + WN;
  unsigned short* Qh  = Wvt + WN;
  unsigned short* Kh  = Qh + HN;
  unsigned short* Vh  = Kh + HN;
  unsigned short* Vts = Vh + HN;

  int n4 = (int)(XN / 4);
  cvt3_f32_bf16<<<dim3(n4 / 256, 3), 256, 0, stream>>>(q, k, v, qb, kb, vb, n4);

  transpose_cvt_w3<<<dim3(32, 32, 3), 256, 0, stream>>>(Wq, Wk, Wv, Wqt, Wkt, Wvt);

  gemm_qkv3<<<dim3(M_ROWS / 128, D_MODEL / 128, 3), 256, 0, stream>>>(
      qb, kb, vb, Wqt, Wkt, Wvt, bq, bk, bv, Qh, Kh, Vh);

  dim3 tv(S_LEN / 64, NHEADS);
  transpose_v<<<tv, 256, 0, stream>>>(Vh, Vts);

  attn_fwd<<<512, 256, 0, stream>>>(Qh, Kh, Vts, out);
}